// Round 1
// baseline (75.593 us; speedup 1.0000x reference)
//
#include <hip/hip_runtime.h>
#include <math.h>

// Echellogram: out[x,y] = emask*sky + src_prof*src + bkg
// sky/src = sum_a exp(-0.5*((lam(x,y)-lam_vector[a])/0.42)^2) * norm * {amps,src_amps}[a]
// lam_vector is a uniform linspace -> Gaussian support spans only ~+-20 indices
// around i0 = round((lam - lam0)/dlam). Truncate at 10 sigma (error < 1e-15 rel).

#define NXd 1024
#define NYd 85
#define NAMPS 1500

__global__ __launch_bounds__(256) void echell_kernel(
    const int*   __restrict__ index_p,
    const float* __restrict__ bkg_p,
    const float* __restrict__ s_coeffs,
    const float* __restrict__ amps,
    const float* __restrict__ smooth_p,
    const float* __restrict__ lam_c,
    const float* __restrict__ p_coeffs,
    const float* __restrict__ src_amps,
    const float* __restrict__ fiducial,
    const float* __restrict__ lam_vector,
    float*       __restrict__ out)
{
    int t = blockIdx.x * blockDim.x + threadIdx.x;
    if (t >= NXd * NYd) return;
    int xi = t / NYd;
    int yi = t - xi * NYd;
    float xx = (float)xi, yy = (float)yi;

    // along-slit coordinate
    float ss = s_coeffs[1] * (yy - s_coeffs[0] - s_coeffs[2] * xx);

    // wavelength surface
    float xn = (xx - 512.0f) * (1.0f / 512.0f);
    float yn = (yy - 42.5f) * (1.0f / 42.5f);
    float cx1 = fiducial[1] * (1.0f + lam_c[1] * 0.01f) * 512.0f;
    float cx2 = 1.0f + lam_c[2];
    float lam = fiducial[0] + lam_c[0] + cx1 * xn
              + cx2 * (2.0f * xn * xn - 1.0f) + lam_c[3] * yn;

    // soft slit mask
    float inv_beta = __expf(-smooth_p[0]);
    float e1 = 1.0f / (1.0f + __expf(-ss * inv_beta));
    float e2 = 1.0f / (1.0f + __expf(-(12.0f - ss) * inv_beta));
    float emask = e1 * e2;

    // windowed Gaussian reduction over amps axis
    float lam0 = lam_vector[0];
    float lamN = lam_vector[NAMPS - 1];
    float dlam = (lamN - lam0) * (1.0f / (float)(NAMPS - 1));
    float inv_dlam = 1.0f / dlam;
    int i0 = (int)floorf((lam - lam0) * inv_dlam + 0.5f);
    int W = (int)ceilf(fabsf(inv_dlam) * 4.2f);   // 10 sigma window (sigma=0.42)
    if (W > NAMPS - 1) W = NAMPS - 1;
    int jlo = i0 - W; if (jlo < 0) jlo = 0;
    int jhi = i0 + W; if (jhi > NAMPS - 1) jhi = NAMPS - 1;

    const float inv_sig = 1.0f / 0.42f;
    float sky = 0.0f, src = 0.0f;
    for (int j = jlo; j <= jhi; ++j) {
        float z = (lam - lam_vector[j]) * inv_sig;
        float p = __expf(-0.5f * z * z);
        sky = fmaf(p, amps[j], sky);
        src = fmaf(p, src_amps[j], src);
    }
    const float norm = 0.3989422804014327f * inv_sig;  // 1/sqrt(2pi)/sigma
    sky *= norm;
    src *= norm;

    // source spatial profile
    int idx = index_p[0];
    float p0 = p_coeffs[2 * idx];
    float p1 = p_coeffs[2 * idx + 1];
    float sigma = __expf(p1);
    float zz = (ss - p0) / sigma;
    // log(sigma) == p1;  0.91893853 = 0.5*log(2*pi)
    float src_prof = __expf(-0.5f * zz * zz - p1 - 0.9189385332046727f);

    out[t] = emask * sky + src_prof * src + bkg_p[0];
}

extern "C" void kernel_launch(void* const* d_in, const int* in_sizes, int n_in,
                              void* d_out, int out_size, void* d_ws, size_t ws_size,
                              hipStream_t stream) {
    const int*   index_p    = (const int*)  d_in[0];
    const float* bkg_p      = (const float*)d_in[1];
    const float* s_coeffs   = (const float*)d_in[2];
    const float* amps       = (const float*)d_in[3];
    const float* smooth_p   = (const float*)d_in[4];
    const float* lam_c      = (const float*)d_in[5];
    const float* p_coeffs   = (const float*)d_in[6];
    const float* src_amps   = (const float*)d_in[7];
    const float* fiducial   = (const float*)d_in[8];
    const float* lam_vector = (const float*)d_in[9];
    float* out = (float*)d_out;

    const int total = NXd * NYd;              // 87040
    const int block = 256;
    const int grid = (total + block - 1) / block;  // 340
    echell_kernel<<<grid, block, 0, stream>>>(
        index_p, bkg_p, s_coeffs, amps, smooth_p, lam_c,
        p_coeffs, src_amps, fiducial, lam_vector, out);
}

// Round 2
// 74.673 us; speedup vs baseline: 1.0123x; 1.0123x over previous
//
#include <hip/hip_runtime.h>
#include <math.h>

// Echellogram: out[x,y] = emask*sky + src_prof*src + bkg
// sky/src = sum_a exp(-0.5*((lam(x,y)-lam_vector[a])/0.42)^2) * norm * {amps,src_amps}[a]
// lam_vector is a uniform linspace (spacing ~0.213, sigma=0.42) -> Gaussian
// support spans only a small index window around i0 = round((lam-lam0)/dlam).
// 5.5-sigma truncation: tail term <= 180*0.95*exp(-15.1) ~ 5e-5, invisible vs
// the 43.2 absmax threshold (measured fp32-vs-np error is already ~8).

#define NXd 1024
#define NYd 85
#define NAMPS 1500

__global__ __launch_bounds__(64) void echell_kernel(
    const int*   __restrict__ index_p,
    const float* __restrict__ bkg_p,
    const float* __restrict__ s_coeffs,
    const float* __restrict__ amps,
    const float* __restrict__ smooth_p,
    const float* __restrict__ lam_c,
    const float* __restrict__ p_coeffs,
    const float* __restrict__ src_amps,
    const float* __restrict__ fiducial,
    const float* __restrict__ lam_vector,
    float*       __restrict__ out)
{
    int t = blockIdx.x * blockDim.x + threadIdx.x;
    if (t >= NXd * NYd) return;
    int xi = t / NYd;
    int yi = t - xi * NYd;
    float xx = (float)xi, yy = (float)yi;

    // along-slit coordinate
    float ss = s_coeffs[1] * (yy - s_coeffs[0] - s_coeffs[2] * xx);

    // wavelength surface
    float xn = (xx - 512.0f) * (1.0f / 512.0f);
    float yn = (yy - 42.5f) * (1.0f / 42.5f);
    float cx1 = fiducial[1] * (1.0f + lam_c[1] * 0.01f) * 512.0f;
    float cx2 = 1.0f + lam_c[2];
    float lam = fiducial[0] + lam_c[0] + cx1 * xn
              + cx2 * (2.0f * xn * xn - 1.0f) + lam_c[3] * yn;

    // soft slit mask
    float inv_beta = __expf(-smooth_p[0]);
    float e1 = 1.0f / (1.0f + __expf(-ss * inv_beta));
    float e2 = 1.0f / (1.0f + __expf(-(12.0f - ss) * inv_beta));
    float emask = e1 * e2;

    // windowed Gaussian reduction over amps axis (5.5 sigma)
    float lam0 = lam_vector[0];
    float lamN = lam_vector[NAMPS - 1];
    float dlam = (lamN - lam0) * (1.0f / (float)(NAMPS - 1));
    float inv_dlam = 1.0f / dlam;
    int i0 = (int)floorf((lam - lam0) * inv_dlam + 0.5f);
    int W = (int)ceilf(fabsf(inv_dlam) * (0.42f * 5.5f));
    if (W > NAMPS - 1) W = NAMPS - 1;
    int jlo = i0 - W; if (jlo < 0) jlo = 0;
    int jhi = i0 + W; if (jhi > NAMPS - 1) jhi = NAMPS - 1;

    const float inv_sig = 1.0f / 0.42f;
    float sky = 0.0f, src = 0.0f;
    #pragma unroll 4
    for (int j = jlo; j <= jhi; ++j) {
        float z = (lam - lam_vector[j]) * inv_sig;
        float p = __expf(-0.5f * z * z);
        sky = fmaf(p, amps[j], sky);
        src = fmaf(p, src_amps[j], src);
    }
    const float norm = 0.3989422804014327f * inv_sig;  // 1/sqrt(2pi)/sigma
    sky *= norm;
    src *= norm;

    // source spatial profile
    int idx = index_p[0];
    float p0 = p_coeffs[2 * idx];
    float p1 = p_coeffs[2 * idx + 1];
    float sigma = __expf(p1);
    float zz = (ss - p0) / sigma;
    float src_prof = __expf(-0.5f * zz * zz - p1 - 0.9189385332046727f);

    out[t] = emask * sky + src_prof * src + bkg_p[0];
}

extern "C" void kernel_launch(void* const* d_in, const int* in_sizes, int n_in,
                              void* d_out, int out_size, void* d_ws, size_t ws_size,
                              hipStream_t stream) {
    const int*   index_p    = (const int*)  d_in[0];
    const float* bkg_p      = (const float*)d_in[1];
    const float* s_coeffs   = (const float*)d_in[2];
    const float* amps       = (const float*)d_in[3];
    const float* smooth_p   = (const float*)d_in[4];
    const float* lam_c      = (const float*)d_in[5];
    const float* p_coeffs   = (const float*)d_in[6];
    const float* src_amps   = (const float*)d_in[7];
    const float* fiducial   = (const float*)d_in[8];
    const float* lam_vector = (const float*)d_in[9];
    float* out = (float*)d_out;

    const int total = NXd * NYd;              // 87040
    const int block = 64;
    const int grid = (total + block - 1) / block;  // 1360
    echell_kernel<<<grid, block, 0, stream>>>(
        index_p, bkg_p, s_coeffs, amps, smooth_p, lam_c,
        p_coeffs, src_amps, fiducial, lam_vector, out);
}